// Round 13
// baseline (306.463 us; speedup 1.0000x reference)
//
#include <hip/hip_runtime.h>

typedef _Float16 f16;
typedef _Float16 half8 __attribute__((ext_vector_type(8)));
typedef _Float16 half4 __attribute__((ext_vector_type(4)));
typedef float f32x4 __attribute__((ext_vector_type(4)));

#define NTHREADS 512
#define XSTR 616

// d_ws layout (bytes):
//  [0, 311296)        W0 pack  [76 k0][256 n][8] f16          (u_gemm B-operand)
//  [311296, 704512)   WT: 24 chunks x [256 n][32 k] f16 (16KB each); chunk = (layer-1)*8 + k/32, TRANSPOSED
//  [704512, 712704)   W4T [16 n][256 k] f16 (n>=3 zero)
//  [712704, 9101312)  U table [16384 cells][256] f16
#define WP_TOTAL_HALFS 356352
#define WT_OFF_H   155648
#define W4_OFF_H   352256
#define U_OFF_BYTES 712704

__device__ __forceinline__ void gload_lds16(const void* g, void* l) {
    __builtin_amdgcn_global_load_lds(
        (const __attribute__((address_space(1))) unsigned int*)g,
        (__attribute__((address_space(3))) unsigned int*)l, 16, 0, 0);
}

__device__ __forceinline__ void stage_chunk(const char* src, void* dst, int nbytes, int wv, int ln) {
    for (int off = wv * 1024; off < nbytes; off += 8192)
        gload_lds16(src + off + (ln << 4), (char*)dst + off);
}

__global__ void prep_weights(const float* __restrict__ W0, const float* __restrict__ W1,
                             const float* __restrict__ W2, const float* __restrict__ W3,
                             const float* __restrict__ W4, f16* __restrict__ wp) {
    int idx = blockIdx.x * 256 + threadIdx.x;
    if (idx >= WP_TOTAL_HALFS) return;
    float v = 0.f;
    if (idx < WT_OFF_H) {                     // L0 pack (u_gemm), unchanged layout
        int k0 = idx >> 11;
        int rem = idx & 2047;
        int n = rem >> 3, j = rem & 7;
        int k = k0 * 8 + j;
        if (k < 587) v = W0[k * 256 + n];
    } else if (idx < W4_OFF_H) {              // WT: transposed [n][k] chunks
        int local = idx - WT_OFF_H;
        int kk = local & 31;
        int rowi = local >> 5;                // chunk*256 + n
        int n = rowi & 255;
        int lc = rowi >> 8;                   // 0..23
        int l = lc >> 3, c = lc & 7;
        int k = c * 32 + kk;
        const float* W = (l == 0) ? W1 : (l == 1) ? W2 : W3;
        v = W[k * 256 + n];
    } else {                                  // W4T [16][256]
        int local = idx - W4_OFF_H;
        int n = local >> 8, k = local & 255;
        v = (n < 3) ? W4[k * 3 + n] : 0.f;
    }
    wp[idx] = (f16)v;
}

// ---- U-table GEMM (unchanged, proven): U[cell][n] = unfold[cell] @ W0[:585] + b0 ----
__global__ __launch_bounds__(NTHREADS, 2)
void u_gemm(const float* __restrict__ feat, const float* __restrict__ mask,
            const float* __restrict__ b0, const f16* __restrict__ wp,
            f16* __restrict__ U) {
    __shared__ __align__(16) f16 sX[64 * XSTR];
    __shared__ __align__(16) f16 sW[2][8192];

    const int tid = threadIdx.x;
    const int wv  = tid >> 6;
    const int ln  = tid & 63;
    const int lo  = ln & 15;
    const int hi  = ln >> 4;

    const int cell0 = blockIdx.x * 64;
    const int y  = cell0 >> 7;
    const int x0 = cell0 & 127;

    stage_chunk((const char*)wp, &sW[0][0], 16384, wv, ln);

    {
        int r = tid & 63;
        int part = tid >> 6;
        #pragma unroll
        for (int o = 0; o < 9; ++o) {
            int ki = o / 3, kj = o % 3;
            int yy = y + ki - 1;
            int xx = x0 + r + kj - 1;
            bool ok = ((unsigned)yy < 128u) && ((unsigned)xx < 128u);
            for (int c = part; c < 65; c += 8) {
                float v = 0.f;
                if (ok) v = (c < 64) ? feat[(c << 14) + (yy << 7) + xx] : mask[(yy << 7) + xx];
                sX[r * XSTR + c * 9 + o] = (f16)v;
            }
        }
    }
    if (tid < 64) {
        for (int k = 585; k < 608; ++k) sX[tid * XSTR + k] = (f16)0.f;
    }
    __syncthreads();

    f32x4 acc[4][2];
    #pragma unroll
    for (int m = 0; m < 4; ++m) { acc[m][0] = f32x4{0,0,0,0}; acc[m][1] = f32x4{0,0,0,0}; }

    for (int g = 0; g < 19; ++g) {
        if (g + 1 < 19)
            stage_chunk((const char*)wp + (g + 1) * 16384, &sW[(g + 1) & 1][0], 16384, wv, ln);
        half8 a[4], b[2];
        #pragma unroll
        for (int t = 0; t < 2; ++t)
            b[t] = *(const half8*)&sW[g & 1][hi * 2048 + ((wv * 2 + t) * 16 + lo) * 8];
        #pragma unroll
        for (int m = 0; m < 4; ++m)
            a[m] = *(const half8*)&sX[(m * 16 + lo) * XSTR + g * 32 + hi * 8];
        #pragma unroll
        for (int m = 0; m < 4; ++m) {
            #pragma unroll
            for (int t = 0; t < 2; ++t)
                acc[m][t] = __builtin_amdgcn_mfma_f32_16x16x32_f16(a[m], b[t], acc[m][t], 0, 0, 0);
        }
        __syncthreads();
    }

    #pragma unroll
    for (int t = 0; t < 2; ++t) {
        int n = (wv * 2 + t) * 16 + lo;
        float bv = b0[n];
        #pragma unroll
        for (int m = 0; m < 4; ++m) {
            #pragma unroll
            for (int i = 0; i < 4; ++i) {
                int cell = cell0 + m * 16 + hi * 4 + i;
                U[cell * 256 + n] = (f16)(acc[m][t][i] + bv);
            }
        }
    }
}

// ---- main: round-11 passing structure (A from L2-resident global), with b[4]->b[2]
//      two-phase to cut ~8 VGPRs and eliminate the residual scratch spill. ----
__global__ __launch_bounds__(NTHREADS, 4)
void liif_main(const float* __restrict__ coord, const float* __restrict__ W0,
               const float* __restrict__ b1, const float* __restrict__ b2,
               const float* __restrict__ b3, const float* __restrict__ b4,
               const f16* __restrict__ wp, const f16* __restrict__ U,
               float* __restrict__ out) {
    __shared__ __align__(16) f16 sAct[128 * 256];      // 64KB, XOR-swizzled rows (stride 512B)
    __shared__ float sRel0[128], sRel1[128], sArea[128];
    __shared__ int   sCell[128];
    __shared__ float sPred[128 * 4];

    const int tid = threadIdx.x;
    const int wv  = tid >> 6;
    const int ln  = tid & 63;
    const int lo  = ln & 15;
    const int hi  = ln >> 4;
    const int ng  = wv & 3;      // n-group (64 cols of W out of 256)
    const int qg  = wv >> 2;     // q-group (64 of 128 rows)

    // meta: exact reference fp32 index math
    if (tid < 128) {
        int r = tid;
        int R = blockIdx.x * 128 + r;
        int q = R >> 2, s = R & 3;
        float c0 = coord[q * 2 + 0];
        float c1 = coord[q * 2 + 1];
        float vx = (s & 2) ? 1.0f : -1.0f;
        float vy = (s & 1) ? 1.0f : -1.0f;
        const float rxy = 0.0078125f;
        const float LOC = (float)(-1.0 + 1e-6);
        const float HIC = (float)( 1.0 - 1e-6);
        float cy = fminf(fmaxf(c0 + vx * rxy + 1e-6f, LOC), HIC);
        float cx = fminf(fmaxf(c1 + vy * rxy + 1e-6f, LOC), HIC);
        int iy = (int)rintf(((cy + 1.0f) * 128.0f - 1.0f) * 0.5f);
        int ix = (int)rintf(((cx + 1.0f) * 128.0f - 1.0f) * 0.5f);
        iy = min(max(iy, 0), 127);
        ix = min(max(ix, 0), 127);
        float qy = -1.0f + ((float)(2 * iy) + 1.0f) * rxy;
        float qx = -1.0f + ((float)(2 * ix) + 1.0f) * rxy;
        float rel0 = (c0 - qy) * 128.0f;
        float rel1 = (c1 - qx) * 128.0f;
        sCell[r] = iy * 128 + ix;
        sRel0[r] = rel0;
        sRel1[r] = rel1;
        sArea[r] = fabsf(rel0 * rel1) + 1e-9f;
    }
    __syncthreads();

    // h0[row][n] = relu(U[cell][n] + rel0*W0[585][n] + rel1*W0[586][n]) -> swizzled sAct
    {
        int row = tid >> 2, p = tid & 3;
        int cell = sCell[row];
        float r0 = sRel0[row], r1 = sRel1[row];
        const half8* up = (const half8*)(U + cell * 256 + p * 64);
        const float* wa = W0 + 585 * 256 + p * 64;
        const float* wb = W0 + 586 * 256 + p * 64;
        char* rowbase = (char*)sAct + row * 512;
        int swz = (row & 7) << 4;
        #pragma unroll
        for (int e = 0; e < 8; ++e) {
            half8 u = up[e];
            half8 hv;
            #pragma unroll
            for (int j = 0; j < 8; ++j) {
                float h = (float)u[j] + r0 * wa[e * 8 + j] + r1 * wb[e * 8 + j];
                hv[j] = (f16)fmaxf(h, 0.f);
            }
            *(half8*)(rowbase + ((p * 128 + e * 16) ^ swz)) = hv;
        }
    }
    __syncthreads();

    // ---- layers 1..3: 24 K=32 chunks, epilogue at g=7,15,23 ----
    const f16* wT = wp + WT_OFF_H;
    const f16* aBase = wT + ng * 2048 + lo * 32 + hi * 8;   // + chunk*8192 + ti*512
    const int rowb = qg * 64 + lo;                          // + tj*16
    const int swzb = (lo & 7) << 4;                         // row&7 invariant under +16
    const char* actb = (const char*)sAct + rowb * 512;

    f32x4 acc[4][4];
    #pragma unroll
    for (int i = 0; i < 4; ++i)
        #pragma unroll
        for (int j = 0; j < 4; ++j) acc[i][j] = f32x4{0,0,0,0};

    #define LOADA(A, c) { \
        const f16* p_ = aBase + (c) * 8192; \
        A[0] = *(const half8*)(p_); \
        A[1] = *(const half8*)(p_ + 512); \
        A[2] = *(const half8*)(p_ + 1024); \
        A[3] = *(const half8*)(p_ + 1536); }

    // two-phase B: phase ph covers qj = ph*2 + {0,1}; b[2] regs reused across phases
    #define LOADB2(B, g, ph) { \
        int byte_ = ((((g) & 7) * 4 + hi) << 4) ^ swzb; \
        B[0] = *(const half8*)(actb + (ph) * 16384 + byte_); \
        B[1] = *(const half8*)(actb + (ph) * 16384 + 8192 + byte_); }

    #define MF2(A, B, ph) { \
        _Pragma("unroll") \
        for (int ni = 0; ni < 4; ++ni) { \
            _Pragma("unroll") \
            for (int t = 0; t < 2; ++t) \
                acc[ni][(ph) * 2 + t] = __builtin_amdgcn_mfma_f32_16x16x32_f16(A[ni], B[t], acc[ni][(ph) * 2 + t], 0, 0, 0); } }

    #define EPI(bias) { \
        __syncthreads(); \
        _Pragma("unroll") \
        for (int ni = 0; ni < 4; ++ni) { \
            int nb_ = ng * 64 + ni * 16 + hi * 4; \
            f32x4 bv_ = *(const f32x4*)((bias) + nb_); \
            _Pragma("unroll") \
            for (int qj = 0; qj < 4; ++qj) { \
                int q_ = qg * 64 + qj * 16 + lo; \
                half4 h_; \
                _Pragma("unroll") \
                for (int r = 0; r < 4; ++r) h_[r] = (f16)fmaxf(acc[ni][qj][r] + bv_[r], 0.f); \
                *(half4*)((char*)sAct + q_ * 512 + ((nb_ * 2) ^ ((q_ & 7) << 4))) = h_; \
                acc[ni][qj] = f32x4{0,0,0,0}; \
            } } \
        __syncthreads(); }

    half8 a[4], b[2];
    for (int g = 0; g < 24; ++g) {
        LOADA(a, g);
        LOADB2(b, g, 0);
        MF2(a, b, 0);
        LOADB2(b, g, 1);
        MF2(a, b, 1);
        if (g == 7)       EPI(b1)
        else if (g == 15) EPI(b2)
        else if (g == 23) EPI(b3)
    }

    // ---- L4: wave wv handles queries wv*16+lo; A = W4T from global ----
    {
        f32x4 acc4 = f32x4{0,0,0,0};
        const f16* w4 = wp + W4_OFF_H + lo * 256 + hi * 8;
        const int row4 = wv * 16 + lo;
        const char* act4 = (const char*)sAct + row4 * 512;
        const int swz4 = (row4 & 7) << 4;
        #pragma unroll
        for (int ks = 0; ks < 8; ++ks) {
            half8 aw = *(const half8*)(w4 + ks * 32);
            half8 bb = *(const half8*)(act4 + ((((ks * 4 + hi) << 4)) ^ swz4));
            acc4 = __builtin_amdgcn_mfma_f32_16x16x32_f16(aw, bb, acc4, 0, 0, 0);
        }
        if (hi == 0) {
            #pragma unroll
            for (int r = 0; r < 3; ++r) sPred[row4 * 4 + r] = acc4[r] + b4[r];
        }
    }
    __syncthreads();

    // local-ensemble combine
    if (tid < 96) {
        int qloc = tid / 3;
        int ch = tid - qloc * 3;
        int rb = qloc * 4;
        float a0_ = sArea[rb + 0], a1_ = sArea[rb + 1], a2_ = sArea[rb + 2], a3_ = sArea[rb + 3];
        float tot = a0_ + a1_ + a2_ + a3_;
        float v = sPred[(rb + 0) * 4 + ch] * (a3_ / tot)
                + sPred[(rb + 1) * 4 + ch] * (a2_ / tot)
                + sPred[(rb + 2) * 4 + ch] * (a1_ / tot)
                + sPred[(rb + 3) * 4 + ch] * (a0_ / tot);
        out[ch * 65536 + blockIdx.x * 32 + qloc] = v;
    }
}

extern "C" void kernel_launch(void* const* d_in, const int* in_sizes, int n_in,
                              void* d_out, int out_size, void* d_ws, size_t ws_size,
                              hipStream_t stream) {
    const float* feat  = (const float*)d_in[0];
    const float* mask  = (const float*)d_in[1];
    const float* coord = (const float*)d_in[3];
    const float* W0 = (const float*)d_in[4];
    const float* b0 = (const float*)d_in[5];
    const float* W1 = (const float*)d_in[6];
    const float* b1 = (const float*)d_in[7];
    const float* W2 = (const float*)d_in[8];
    const float* b2 = (const float*)d_in[9];
    const float* W3 = (const float*)d_in[10];
    const float* b3 = (const float*)d_in[11];
    const float* W4 = (const float*)d_in[12];
    const float* b4 = (const float*)d_in[13];
    f16* wp = (f16*)d_ws;
    f16* U  = (f16*)((char*)d_ws + U_OFF_BYTES);
    float* outp = (float*)d_out;

    prep_weights<<<(WP_TOTAL_HALFS + 255) / 256, 256, 0, stream>>>(W0, W1, W2, W3, W4, wp);
    u_gemm<<<256, NTHREADS, 0, stream>>>(feat, mask, b0, wp, U);
    liif_main<<<2048, NTHREADS, 0, stream>>>(coord, W0, b1, b2, b3, b4, wp, U, outp);
}